// Round 7
// baseline (373.514 us; speedup 1.0000x reference)
//
#include <hip/hip_runtime.h>
#include <hip/hip_bf16.h>

typedef float  float4v __attribute__((ext_vector_type(4)));
typedef short  short8v __attribute__((ext_vector_type(8)));
typedef short  short4v __attribute__((ext_vector_type(4)));
typedef __bf16 bf16x8  __attribute__((ext_vector_type(8)));
typedef float  f32x4   __attribute__((ext_vector_type(4)));

constexpr int NB = 512, T = 64, DIN = 1024, DOUT = 1024;
constexpr int BM = 128, BN = 128, BK = 64;

// ---- workspace layout (bf16 path) ----
constexpr size_t ABF_BYTES = (size_t)NB * T * DIN * 2;   // 67,108,864
constexpr size_t WN_BYTES  = (size_t)DOUT * DIN * 2;     // 2,097,152
constexpr size_t WS_BF16   = ABF_BYTES + WN_BYTES;       // ~69 MB

__device__ __forceinline__ short f2bf_rne(float x) {
    return __builtin_bit_cast(short, __float2bfloat16(x));
}
__device__ __forceinline__ short f2bf_trunc(float x) {   // exact for {0,1}
    return (short)(__builtin_bit_cast(unsigned int, x) >> 16);
}
__device__ __forceinline__ void load_lds_16B(const void* g, void* l) {
    __builtin_amdgcn_global_load_lds(
        (const __attribute__((address_space(1))) unsigned int*)g,
        (__attribute__((address_space(3))) unsigned int*)l, 16, 0, 0);
}

// ---- prepass: A fp32 (binary) -> bf16 via exact truncation. 8 elems/thread.
__global__ void __launch_bounds__(256)
prep_a_kernel(const float* __restrict__ A, short* __restrict__ Abf) {
    int idx = blockIdx.x * 256 + threadIdx.x;            // 8-elem group
    const float4v* p = (const float4v*)A + (size_t)idx * 2;
    float4v v0 = __builtin_nontemporal_load(p);
    float4v v1 = __builtin_nontemporal_load(p + 1);
    short8v s;
    #pragma unroll
    for (int j = 0; j < 4; j++) {
        s[j]     = f2bf_trunc(v0[j]);
        s[j + 4] = f2bf_trunc(v1[j]);
    }
    *((short8v*)Abf + idx) = s;                          // cached: re-read soon
}

// ---- prepass: Wn = bf16(W * gamma/sqrt(rvar))
__global__ void __launch_bounds__(256)
fold_w_kernel(const float* __restrict__ W, const float* __restrict__ gamma,
              const float* __restrict__ rvar, short* __restrict__ Wn) {
    int idx = blockIdx.x * 256 + threadIdx.x;            // float4 group
    int o = idx >> 8;
    float r = gamma[o] / sqrtf(rvar[o]);
    float4v w = ((const float4v*)W)[idx];
    short4v s;
    #pragma unroll
    for (int j = 0; j < 4; j++) s[j] = f2bf_rne(w[j] * r);
    ((short4v*)Wn)[idx] = s;
}

// ---- main: 128x128 tile; A via LDS-DMA (XCD-local: grid (256,8) puts all
// column-blocks of a sample-pair on one XCD), B direct global->VGPR
// (2 MB Wn becomes resident in every XCD's L2 after first touch).
__global__ void __launch_bounds__(256, 3)
snn_gemm_if_v7(const short* __restrict__ Abf,  // (N*T, DIN) bf16 {0,1}
               const short* __restrict__ Wn,   // (DOUT, DIN) bf16, BN-folded
               const float* __restrict__ bias, const float* __restrict__ gamma,
               const float* __restrict__ beta, const float* __restrict__ rmean,
               const float* __restrict__ rvar, float* __restrict__ out) {
    __shared__ __align__(16) char smem[32768];   // A staging 16K; potS union 32K
    __shared__ float bstepS[BN];
    char* AsS   = smem;                          // 1024 slots x 16B
    float* potS = (float*)smem;                  // 64 x 128 fp32 (epilogue)

    const int tid = threadIdx.x;
    const int bs  = blockIdx.x;                  // sample pair; XCD = bs % 8
    const int oB  = blockIdx.y * BN;             // column block

    if (tid < BN) {
        int o = oB + tid;
        float r = gamma[o] / sqrtf(rvar[o]);
        bstepS[tid] = ((bias[o] - rmean[o]) * r + beta[o]) * (1.0f / 64.0f);
    }

    const int lane = tid & 63;
    const int wv   = tid >> 6;
    const int wr   = wv & 1;      // 64-row half
    const int wc   = wv >> 1;     // 64-col half
    const int l15  = lane & 15;
    const int quad = lane >> 4;

    // A staging: slot s -> row=s>>3, chunk=(s&7)^(row&7)
    int srcA[4];
    #pragma unroll
    for (int i = 0; i < 4; i++) {
        int s = i * 256 + tid, row = s >> 3, ck = (s & 7) ^ (row & 7);
        srcA[i] = row * (DIN * 2) + ck * 16;
    }
    // A fragment LDS offsets
    int aOff[4][2];
    #pragma unroll
    for (int i = 0; i < 4; i++) {
        int ra = wr * 64 + i * 16 + l15;
        #pragma unroll
        for (int ks = 0; ks < 2; ks++) {
            int c = ks * 4 + quad;
            aOff[i][ks] = (ra * 8 + (c ^ (ra & 7))) * 16;
        }
    }
    // B direct per-lane base: row = oB + wc*64 + ni*16 + l15, k = kb + ks*32 + quad*8
    const short* Bl = Wn + (size_t)(oB + wc * 64 + l15) * DIN + quad * 8;

    f32x4 acc[4][4] = {};
    const char* Ab = (const char*)(Abf + (size_t)bs * BM * DIN);

    for (int kb = 0; kb < DIN; kb += BK) {
        __syncthreads();                         // prev tile ds_reads done
        #pragma unroll
        for (int i = 0; i < 4; i++)
            load_lds_16B(Ab + srcA[i] + kb * 2, AsS + (i * 256 + tid) * 16);
        // B fragments straight from global (L2-resident after warm-up)
        short8v bfr[2][4];
        #pragma unroll
        for (int ks = 0; ks < 2; ks++)
            #pragma unroll
            for (int ni = 0; ni < 4; ni++)
                bfr[ks][ni] = *(const short8v*)(Bl + (size_t)ni * 16 * DIN + kb + ks * 32);
        __syncthreads();                         // drains DMA + B loads

        #pragma unroll
        for (int ks = 0; ks < 2; ks++) {
            bf16x8 af[4];
            #pragma unroll
            for (int mi = 0; mi < 4; mi++)
                af[mi] = __builtin_bit_cast(bf16x8, *(const short8v*)(AsS + aOff[mi][ks]));
            #pragma unroll
            for (int mi = 0; mi < 4; mi++)
                #pragma unroll
                for (int ni = 0; ni < 4; ni++)
                    acc[mi][ni] = __builtin_amdgcn_mfma_f32_16x16x32_bf16(
                        af[mi], __builtin_bit_cast(bf16x8, bfr[ks][ni]),
                        acc[mi][ni], 0, 0, 0);
        }
    }

    __syncthreads();                             // staging free; potS aliases it

    // two 64-row chunks: acc -> potS (quad-swizzled banks), then IF scan
    #pragma unroll 1
    for (int s = 0; s < 2; s++) {
        if (wr == s) {
            #pragma unroll
            for (int mi = 0; mi < 4; mi++)
                #pragma unroll
                for (int ni = 0; ni < 4; ni++)
                    #pragma unroll
                    for (int r = 0; r < 4; r++) {
                        int row = mi * 16 + quad * 4 + r;
                        int col = (wc * 64 + ni * 16 + l15) ^ (quad << 3);
                        potS[row * BN + col] = acc[mi][ni][r];
                    }
        }
        __syncthreads();
        if (tid < BN) {
            int n = bs * 2 + s;
            float pot = 0.f, cnt = 0.f;
            const float bst = bstepS[tid];
            float* so = out + (size_t)n * T * DOUT + oB + tid;
            for (int t = 0; t < T; t++) {
                pot += potS[t * BN + (tid ^ (((t >> 2) & 3) << 3))] + bst;
                float spk = (pot >= 1.0f) ? 1.0f : 0.0f;
                pot -= spk;
                cnt += spk;
                __builtin_nontemporal_store(spk, so + (size_t)t * DOUT);
            }
            __builtin_nontemporal_store(
                cnt, out + (size_t)NB * T * DOUT + (size_t)n * DOUT + oB + tid);
        }
        __syncthreads();
    }
}

// ===================== fallback (round-2 proven path) =====================

constexpr int LDA_F = 72;
constexpr int A_BYTES_F = BM * LDA_F * 2;
constexpr int SMEM_F = A_BYTES_F + BN * BK * 2;

template <bool PREFOLD>
__global__ void __launch_bounds__(256)
snn_gemm_if(const float* __restrict__ A, const float* __restrict__ W,
            const short* __restrict__ Wn,
            const float* __restrict__ bias, const float* __restrict__ gamma,
            const float* __restrict__ beta, const float* __restrict__ rmean,
            const float* __restrict__ rvar, float* __restrict__ out) {
    __shared__ __align__(16) char smem[SMEM_F];
    __shared__ float ratioS[BN];
    __shared__ float bstepS[BN];
    short* AsS  = (short*)smem;
    short* BsS  = (short*)(smem + A_BYTES_F);
    float* potS = (float*)smem;

    const int tid   = threadIdx.x;
    const int by    = blockIdx.y;
    const int oBase = blockIdx.x * BN;

    if (tid < BN) {
        int o = oBase + tid;
        float r = gamma[o] / sqrtf(rvar[o]);
        ratioS[tid] = r;
        bstepS[tid] = ((bias[o] - rmean[o]) * r + beta[o]) * (1.0f / 64.0f);
    }
    __syncthreads();

    const int lane = tid & 63;
    const int wv   = tid >> 6;
    const int wr   = wv & 1;
    const int wc   = wv >> 1;
    const int l15  = lane & 15;
    const int quad = lane >> 4;

    f32x4 acc[4][4] = {};
    const float* Ab = A + (size_t)by * BM * DIN;

    for (int kb = 0; kb < DIN; kb += BK) {
        float4v av[4][2];
        #pragma unroll
        for (int i = 0; i < 4; i++) {
            int g = i * 256 + tid;
            int r = g >> 3, k8 = g & 7;
            const float4v* p = (const float4v*)(Ab + (size_t)r * DIN + kb + k8 * 8);
            av[i][0] = p[0];
            av[i][1] = p[1];
        }
        float4v bv[4][2];
        if constexpr (!PREFOLD) {
            #pragma unroll
            for (int i = 0; i < 4; i++) {
                int slot = i * 256 + tid;
                int r = slot >> 3, k8 = (slot & 7) ^ (r & 7);
                const float4v* p = (const float4v*)(W + (size_t)(oBase + r) * DIN + kb + k8 * 8);
                bv[i][0] = p[0];
                bv[i][1] = p[1];
            }
        }
        __syncthreads();

        if constexpr (PREFOLD) {
            #pragma unroll
            for (int i = 0; i < 4; i++) {
                int slot = i * 256 + tid;
                int r = slot >> 3, k8 = (slot & 7) ^ (r & 7);
                load_lds_16B(Wn + (size_t)(oBase + r) * DIN + kb + k8 * 8,
                             BsS + (size_t)slot * 8);
            }
        } else {
            #pragma unroll
            for (int i = 0; i < 4; i++) {
                int slot = i * 256 + tid;
                int r = slot >> 3;
                float rt = ratioS[r];
                short8v s;
                #pragma unroll
                for (int j = 0; j < 4; j++) {
                    s[j]     = f2bf_rne(bv[i][0][j] * rt);
                    s[j + 4] = f2bf_rne(bv[i][1][j] * rt);
                }
                *(short8v*)(BsS + (size_t)slot * 8) = s;
            }
        }
        #pragma unroll
        for (int i = 0; i < 4; i++) {
            int g = i * 256 + tid;
            int r = g >> 3, k8 = g & 7;
            short8v s;
            #pragma unroll
            for (int j = 0; j < 4; j++) {
                s[j]     = f2bf_trunc(av[i][0][j]);
                s[j + 4] = f2bf_trunc(av[i][1][j]);
            }
            *(short8v*)(&AsS[r * LDA_F + k8 * 8]) = s;
        }
        __syncthreads();

        #pragma unroll
        for (int ks = 0; ks < 2; ks++) {
            bf16x8 af[4], bfv[4];
            #pragma unroll
            for (int mi = 0; mi < 4; mi++)
                af[mi] = __builtin_bit_cast(bf16x8,
                    *(const short8v*)(&AsS[(wr * 64 + mi * 16 + l15) * LDA_F + ks * 32 + quad * 8]));
            #pragma unroll
            for (int ni = 0; ni < 4; ni++) {
                int row  = wc * 64 + ni * 16 + l15;
                int slot = row * 8 + ((ks * 4 + quad) ^ (l15 & 7));
                bfv[ni] = __builtin_bit_cast(bf16x8, *(const short8v*)(BsS + (size_t)slot * 8));
            }
            #pragma unroll
            for (int mi = 0; mi < 4; mi++)
                #pragma unroll
                for (int ni = 0; ni < 4; ni++)
                    acc[mi][ni] = __builtin_amdgcn_mfma_f32_16x16x32_bf16(
                        af[mi], bfv[ni], acc[mi][ni], 0, 0, 0);
        }
    }

    __syncthreads();

    #pragma unroll 1
    for (int s = 0; s < 2; s++) {
        if (wr == s) {
            #pragma unroll
            for (int mi = 0; mi < 4; mi++)
                #pragma unroll
                for (int ni = 0; ni < 4; ni++)
                    #pragma unroll
                    for (int r = 0; r < 4; r++)
                        potS[(mi * 16 + quad * 4 + r) * BN + wc * 64 + ni * 16 + l15] =
                            acc[mi][ni][r];
        }
        __syncthreads();
        if (tid < BN) {
            int n = by * 2 + s;
            float pot = 0.f, cnt = 0.f;
            const float bst = bstepS[tid];
            float* so = out + (size_t)n * T * DOUT + oBase + tid;
            for (int t = 0; t < T; t++) {
                pot += potS[t * BN + tid] + bst;
                float spk = (pot >= 1.0f) ? 1.0f : 0.0f;
                pot -= spk;
                cnt += spk;
                so[(size_t)t * DOUT] = spk;
            }
            out[(size_t)NB * T * DOUT + (size_t)n * DOUT + oBase + tid] = cnt;
        }
        __syncthreads();
    }
}

extern "C" void kernel_launch(void* const* d_in, const int* in_sizes, int n_in,
                              void* d_out, int out_size, void* d_ws, size_t ws_size,
                              hipStream_t stream) {
    const float* A     = (const float*)d_in[0];
    // d_in[1] (input_features_sc) feeds only the un-returned ANN path — dead.
    const float* W     = (const float*)d_in[2];
    const float* bias  = (const float*)d_in[3];
    const float* gamma = (const float*)d_in[4];
    const float* beta  = (const float*)d_in[5];
    const float* rmean = (const float*)d_in[6];
    const float* rvar  = (const float*)d_in[7];
    float* out = (float*)d_out;

    if (d_ws != nullptr && ws_size >= WS_BF16) {
        short* Abf = (short*)d_ws;
        short* Wn  = (short*)((char*)d_ws + ABF_BYTES);
        prep_a_kernel<<<(NB * T * DIN) / 8 / 256, 256, 0, stream>>>(A, Abf);
        fold_w_kernel<<<DOUT * DIN / 4 / 256, 256, 0, stream>>>(W, gamma, rvar, Wn);
        dim3 grid(NB / 2, DOUT / BN);   // (256, 8): same-sample blocks -> same XCD
        snn_gemm_if_v7<<<grid, 256, 0, stream>>>(Abf, Wn, bias, gamma, beta,
                                                 rmean, rvar, out);
    } else if (d_ws != nullptr && ws_size >= WN_BYTES) {
        short* Wn = (short*)d_ws;
        fold_w_kernel<<<DOUT * DIN / 4 / 256, 256, 0, stream>>>(W, gamma, rvar, Wn);
        dim3 grid(DOUT / BN, NB / 2);
        snn_gemm_if<true><<<grid, 256, 0, stream>>>(A, W, Wn, bias, gamma, beta,
                                                    rmean, rvar, out);
    } else {
        dim3 grid(DOUT / BN, NB / 2);
        snn_gemm_if<false><<<grid, 256, 0, stream>>>(A, W, nullptr, bias, gamma, beta,
                                                     rmean, rvar, out);
    }
}

// Round 8
// 371.136 us; speedup vs baseline: 1.0064x; 1.0064x over previous
//
#include <hip/hip_runtime.h>
#include <hip/hip_bf16.h>

typedef float  float4v __attribute__((ext_vector_type(4)));
typedef short  short8v __attribute__((ext_vector_type(8)));
typedef short  short4v __attribute__((ext_vector_type(4)));
typedef __bf16 bf16x8  __attribute__((ext_vector_type(8)));
typedef float  f32x4   __attribute__((ext_vector_type(4)));

constexpr int NB = 512, T = 64, DIN = 1024, DOUT = 1024;
constexpr int BM = 128, BN = 128, BK = 64;

// ---- workspace layout (bf16 path) ----
constexpr size_t ABF_BYTES = (size_t)NB * T * DIN * 2;   // 67,108,864
constexpr size_t WN_BYTES  = (size_t)DOUT * DIN * 2;     // 2,097,152
constexpr size_t WS_BF16   = ABF_BYTES + WN_BYTES;       // ~69 MB

__device__ __forceinline__ short f2bf_rne(float x) {
    return __builtin_bit_cast(short, __float2bfloat16(x));
}
__device__ __forceinline__ short f2bf_trunc(float x) {   // exact for {0,1}
    return (short)(__builtin_bit_cast(unsigned int, x) >> 16);
}
__device__ __forceinline__ void load_lds_16B(const void* g, void* l) {
    __builtin_amdgcn_global_load_lds(
        (const __attribute__((address_space(1))) unsigned int*)g,
        (__attribute__((address_space(3))) unsigned int*)l, 16, 0, 0);
}

// ---- prepass: A fp32 (binary) -> bf16 via exact truncation. 8 elems/thread.
__global__ void __launch_bounds__(256)
prep_a_kernel(const float* __restrict__ A, short* __restrict__ Abf) {
    int idx = blockIdx.x * 256 + threadIdx.x;            // 8-elem group
    const float4v* p = (const float4v*)A + (size_t)idx * 2;
    float4v v0 = __builtin_nontemporal_load(p);
    float4v v1 = __builtin_nontemporal_load(p + 1);
    short8v s;
    #pragma unroll
    for (int j = 0; j < 4; j++) {
        s[j]     = f2bf_trunc(v0[j]);
        s[j + 4] = f2bf_trunc(v1[j]);
    }
    *((short8v*)Abf + idx) = s;                          // cached: re-read soon
}

// ---- prepass: Wn = bf16(W * gamma/sqrt(rvar))
__global__ void __launch_bounds__(256)
fold_w_kernel(const float* __restrict__ W, const float* __restrict__ gamma,
              const float* __restrict__ rvar, short* __restrict__ Wn) {
    int idx = blockIdx.x * 256 + threadIdx.x;            // float4 group
    int o = idx >> 8;
    float r = gamma[o] / sqrtf(rvar[o]);
    float4v w = ((const float4v*)W)[idx];
    short4v s;
    #pragma unroll
    for (int j = 0; j < 4; j++) s[j] = f2bf_rne(w[j] * r);
    ((short4v*)Wn)[idx] = s;
}

// ---- main: 128x128 tile; A via LDS-DMA (grid (256,8): all column-blocks of a
// sample-pair share an XCD), B direct global->VGPR with ONE-ITERATION
// SOFTWARE PREFETCH so the barrier's vmcnt drain never waits on B latency.
__global__ void __launch_bounds__(256, 3)
snn_gemm_if_v8(const short* __restrict__ Abf,  // (N*T, DIN) bf16 {0,1}
               const short* __restrict__ Wn,   // (DOUT, DIN) bf16, BN-folded
               const float* __restrict__ bias, const float* __restrict__ gamma,
               const float* __restrict__ beta, const float* __restrict__ rmean,
               const float* __restrict__ rvar, float* __restrict__ out) {
    __shared__ __align__(16) char smem[32768];   // A staging 16K; potS union 32K
    __shared__ float bstepS[BN];
    char* AsS   = smem;                          // 1024 slots x 16B
    float* potS = (float*)smem;                  // 64 x 128 fp32 (epilogue)

    const int tid = threadIdx.x;
    const int bs  = blockIdx.x;                  // sample pair; XCD = bs % 8
    const int oB  = blockIdx.y * BN;             // column block

    if (tid < BN) {
        int o = oB + tid;
        float r = gamma[o] / sqrtf(rvar[o]);
        bstepS[tid] = ((bias[o] - rmean[o]) * r + beta[o]) * (1.0f / 64.0f);
    }

    const int lane = tid & 63;
    const int wv   = tid >> 6;
    const int wr   = wv & 1;      // 64-row half
    const int wc   = wv >> 1;     // 64-col half
    const int l15  = lane & 15;
    const int quad = lane >> 4;

    // A staging: slot s -> row=s>>3, chunk=(s&7)^(row&7)
    int srcA[4];
    #pragma unroll
    for (int i = 0; i < 4; i++) {
        int s = i * 256 + tid, row = s >> 3, ck = (s & 7) ^ (row & 7);
        srcA[i] = row * (DIN * 2) + ck * 16;
    }
    // A fragment LDS offsets
    int aOff[4][2];
    #pragma unroll
    for (int i = 0; i < 4; i++) {
        int ra = wr * 64 + i * 16 + l15;
        #pragma unroll
        for (int ks = 0; ks < 2; ks++) {
            int c = ks * 4 + quad;
            aOff[i][ks] = (ra * 8 + (c ^ (ra & 7))) * 16;
        }
    }
    // B per-lane base: row = oB + wc*64 + ni*16 + l15, k = kb + ks*32 + quad*8
    const short* Bl = Wn + (size_t)(oB + wc * 64 + l15) * DIN + quad * 8;

    f32x4 acc[4][4] = {};
    const char* Ab = (const char*)(Abf + (size_t)bs * BM * DIN);

    short8v b0[2][4], b1[2][4];   // double-buffered B fragments (registers)
    #pragma unroll
    for (int ks = 0; ks < 2; ks++)
        #pragma unroll
        for (int ni = 0; ni < 4; ni++)
            b0[ks][ni] = *(const short8v*)(Bl + (size_t)ni * 16 * DIN + ks * 32);

    // 8 outer iterations, each covering two BK=64 tiles (buffers alternate)
    #pragma unroll 1
    for (int kb = 0; kb < DIN; kb += 2 * BK) {
        // ---- even tile: consume b0, prefetch b1 for kb+BK
        __syncthreads();                         // LDS reuse safe
        #pragma unroll
        for (int i = 0; i < 4; i++)
            load_lds_16B(Ab + srcA[i] + kb * 2, AsS + (i * 256 + tid) * 16);
        __syncthreads();                         // A staged (b-prefetch long done)
        #pragma unroll
        for (int ks = 0; ks < 2; ks++)
            #pragma unroll
            for (int ni = 0; ni < 4; ni++)
                b1[ks][ni] = *(const short8v*)(Bl + (size_t)ni * 16 * DIN + (kb + BK) + ks * 32);
        #pragma unroll
        for (int ks = 0; ks < 2; ks++) {
            bf16x8 af[4];
            #pragma unroll
            for (int mi = 0; mi < 4; mi++)
                af[mi] = __builtin_bit_cast(bf16x8, *(const short8v*)(AsS + aOff[mi][ks]));
            #pragma unroll
            for (int mi = 0; mi < 4; mi++)
                #pragma unroll
                for (int ni = 0; ni < 4; ni++)
                    acc[mi][ni] = __builtin_amdgcn_mfma_f32_16x16x32_bf16(
                        af[mi], __builtin_bit_cast(bf16x8, b0[ks][ni]),
                        acc[mi][ni], 0, 0, 0);
        }
        // ---- odd tile: consume b1, prefetch b0 for kb+2*BK
        __syncthreads();
        #pragma unroll
        for (int i = 0; i < 4; i++)
            load_lds_16B(Ab + srcA[i] + (kb + BK) * 2, AsS + (i * 256 + tid) * 16);
        __syncthreads();
        if (kb + 2 * BK < DIN) {
            #pragma unroll
            for (int ks = 0; ks < 2; ks++)
                #pragma unroll
                for (int ni = 0; ni < 4; ni++)
                    b0[ks][ni] = *(const short8v*)(Bl + (size_t)ni * 16 * DIN + (kb + 2 * BK) + ks * 32);
        }
        #pragma unroll
        for (int ks = 0; ks < 2; ks++) {
            bf16x8 af[4];
            #pragma unroll
            for (int mi = 0; mi < 4; mi++)
                af[mi] = __builtin_bit_cast(bf16x8, *(const short8v*)(AsS + aOff[mi][ks]));
            #pragma unroll
            for (int mi = 0; mi < 4; mi++)
                #pragma unroll
                for (int ni = 0; ni < 4; ni++)
                    acc[mi][ni] = __builtin_amdgcn_mfma_f32_16x16x32_bf16(
                        af[mi], __builtin_bit_cast(bf16x8, b1[ks][ni]),
                        acc[mi][ni], 0, 0, 0);
        }
    }

    __syncthreads();                             // staging free; potS aliases it

    // two 64-row chunks: acc -> potS (quad-swizzled banks), then IF scan
    #pragma unroll 1
    for (int s = 0; s < 2; s++) {
        if (wr == s) {
            #pragma unroll
            for (int mi = 0; mi < 4; mi++)
                #pragma unroll
                for (int ni = 0; ni < 4; ni++)
                    #pragma unroll
                    for (int r = 0; r < 4; r++) {
                        int row = mi * 16 + quad * 4 + r;
                        int col = (wc * 64 + ni * 16 + l15) ^ (quad << 3);
                        potS[row * BN + col] = acc[mi][ni][r];
                    }
        }
        __syncthreads();
        if (tid < BN) {
            int n = bs * 2 + s;
            float pot = 0.f, cnt = 0.f;
            const float bst = bstepS[tid];
            float* so = out + (size_t)n * T * DOUT + oB + tid;
            for (int t = 0; t < T; t++) {
                pot += potS[t * BN + (tid ^ (((t >> 2) & 3) << 3))] + bst;
                float spk = (pot >= 1.0f) ? 1.0f : 0.0f;
                pot -= spk;
                cnt += spk;
                __builtin_nontemporal_store(spk, so + (size_t)t * DOUT);
            }
            __builtin_nontemporal_store(
                cnt, out + (size_t)NB * T * DOUT + (size_t)n * DOUT + oB + tid);
        }
        __syncthreads();
    }
}

// ===================== fallback (round-2 proven path) =====================

constexpr int LDA_F = 72;
constexpr int A_BYTES_F = BM * LDA_F * 2;
constexpr int SMEM_F = A_BYTES_F + BN * BK * 2;

template <bool PREFOLD>
__global__ void __launch_bounds__(256)
snn_gemm_if(const float* __restrict__ A, const float* __restrict__ W,
            const short* __restrict__ Wn,
            const float* __restrict__ bias, const float* __restrict__ gamma,
            const float* __restrict__ beta, const float* __restrict__ rmean,
            const float* __restrict__ rvar, float* __restrict__ out) {
    __shared__ __align__(16) char smem[SMEM_F];
    __shared__ float ratioS[BN];
    __shared__ float bstepS[BN];
    short* AsS  = (short*)smem;
    short* BsS  = (short*)(smem + A_BYTES_F);
    float* potS = (float*)smem;

    const int tid   = threadIdx.x;
    const int by    = blockIdx.y;
    const int oBase = blockIdx.x * BN;

    if (tid < BN) {
        int o = oBase + tid;
        float r = gamma[o] / sqrtf(rvar[o]);
        ratioS[tid] = r;
        bstepS[tid] = ((bias[o] - rmean[o]) * r + beta[o]) * (1.0f / 64.0f);
    }
    __syncthreads();

    const int lane = tid & 63;
    const int wv   = tid >> 6;
    const int wr   = wv & 1;
    const int wc   = wv >> 1;
    const int l15  = lane & 15;
    const int quad = lane >> 4;

    f32x4 acc[4][4] = {};
    const float* Ab = A + (size_t)by * BM * DIN;

    for (int kb = 0; kb < DIN; kb += BK) {
        float4v av[4][2];
        #pragma unroll
        for (int i = 0; i < 4; i++) {
            int g = i * 256 + tid;
            int r = g >> 3, k8 = g & 7;
            const float4v* p = (const float4v*)(Ab + (size_t)r * DIN + kb + k8 * 8);
            av[i][0] = p[0];
            av[i][1] = p[1];
        }
        float4v bv[4][2];
        if constexpr (!PREFOLD) {
            #pragma unroll
            for (int i = 0; i < 4; i++) {
                int slot = i * 256 + tid;
                int r = slot >> 3, k8 = (slot & 7) ^ (r & 7);
                const float4v* p = (const float4v*)(W + (size_t)(oBase + r) * DIN + kb + k8 * 8);
                bv[i][0] = p[0];
                bv[i][1] = p[1];
            }
        }
        __syncthreads();

        if constexpr (PREFOLD) {
            #pragma unroll
            for (int i = 0; i < 4; i++) {
                int slot = i * 256 + tid;
                int r = slot >> 3, k8 = (slot & 7) ^ (r & 7);
                load_lds_16B(Wn + (size_t)(oBase + r) * DIN + kb + k8 * 8,
                             BsS + (size_t)slot * 8);
            }
        } else {
            #pragma unroll
            for (int i = 0; i < 4; i++) {
                int slot = i * 256 + tid;
                int r = slot >> 3;
                float rt = ratioS[r];
                short8v s;
                #pragma unroll
                for (int j = 0; j < 4; j++) {
                    s[j]     = f2bf_rne(bv[i][0][j] * rt);
                    s[j + 4] = f2bf_rne(bv[i][1][j] * rt);
                }
                *(short8v*)(BsS + (size_t)slot * 8) = s;
            }
        }
        #pragma unroll
        for (int i = 0; i < 4; i++) {
            int g = i * 256 + tid;
            int r = g >> 3, k8 = g & 7;
            short8v s;
            #pragma unroll
            for (int j = 0; j < 4; j++) {
                s[j]     = f2bf_trunc(av[i][0][j]);
                s[j + 4] = f2bf_trunc(av[i][1][j]);
            }
            *(short8v*)(&AsS[r * LDA_F + k8 * 8]) = s;
        }
        __syncthreads();

        #pragma unroll
        for (int ks = 0; ks < 2; ks++) {
            bf16x8 af[4], bfv[4];
            #pragma unroll
            for (int mi = 0; mi < 4; mi++)
                af[mi] = __builtin_bit_cast(bf16x8,
                    *(const short8v*)(&AsS[(wr * 64 + mi * 16 + l15) * LDA_F + ks * 32 + quad * 8]));
            #pragma unroll
            for (int ni = 0; ni < 4; ni++) {
                int row  = wc * 64 + ni * 16 + l15;
                int slot = row * 8 + ((ks * 4 + quad) ^ (l15 & 7));
                bfv[ni] = __builtin_bit_cast(bf16x8, *(const short8v*)(BsS + (size_t)slot * 8));
            }
            #pragma unroll
            for (int mi = 0; mi < 4; mi++)
                #pragma unroll
                for (int ni = 0; ni < 4; ni++)
                    acc[mi][ni] = __builtin_amdgcn_mfma_f32_16x16x32_bf16(
                        af[mi], bfv[ni], acc[mi][ni], 0, 0, 0);
        }
    }

    __syncthreads();

    #pragma unroll 1
    for (int s = 0; s < 2; s++) {
        if (wr == s) {
            #pragma unroll
            for (int mi = 0; mi < 4; mi++)
                #pragma unroll
                for (int ni = 0; ni < 4; ni++)
                    #pragma unroll
                    for (int r = 0; r < 4; r++)
                        potS[(mi * 16 + quad * 4 + r) * BN + wc * 64 + ni * 16 + l15] =
                            acc[mi][ni][r];
        }
        __syncthreads();
        if (tid < BN) {
            int n = by * 2 + s;
            float pot = 0.f, cnt = 0.f;
            const float bst = bstepS[tid];
            float* so = out + (size_t)n * T * DOUT + oBase + tid;
            for (int t = 0; t < T; t++) {
                pot += potS[t * BN + tid] + bst;
                float spk = (pot >= 1.0f) ? 1.0f : 0.0f;
                pot -= spk;
                cnt += spk;
                so[(size_t)t * DOUT] = spk;
            }
            out[(size_t)NB * T * DOUT + (size_t)n * DOUT + oBase + tid] = cnt;
        }
        __syncthreads();
    }
}

extern "C" void kernel_launch(void* const* d_in, const int* in_sizes, int n_in,
                              void* d_out, int out_size, void* d_ws, size_t ws_size,
                              hipStream_t stream) {
    const float* A     = (const float*)d_in[0];
    // d_in[1] (input_features_sc) feeds only the un-returned ANN path — dead.
    const float* W     = (const float*)d_in[2];
    const float* bias  = (const float*)d_in[3];
    const float* gamma = (const float*)d_in[4];
    const float* beta  = (const float*)d_in[5];
    const float* rmean = (const float*)d_in[6];
    const float* rvar  = (const float*)d_in[7];
    float* out = (float*)d_out;

    if (d_ws != nullptr && ws_size >= WS_BF16) {
        short* Abf = (short*)d_ws;
        short* Wn  = (short*)((char*)d_ws + ABF_BYTES);
        prep_a_kernel<<<(NB * T * DIN) / 8 / 256, 256, 0, stream>>>(A, Abf);
        fold_w_kernel<<<DOUT * DIN / 4 / 256, 256, 0, stream>>>(W, gamma, rvar, Wn);
        dim3 grid(NB / 2, DOUT / BN);   // (256, 8): same-sample blocks -> same XCD
        snn_gemm_if_v8<<<grid, 256, 0, stream>>>(Abf, Wn, bias, gamma, beta,
                                                 rmean, rvar, out);
    } else if (d_ws != nullptr && ws_size >= WN_BYTES) {
        short* Wn = (short*)d_ws;
        fold_w_kernel<<<DOUT * DIN / 4 / 256, 256, 0, stream>>>(W, gamma, rvar, Wn);
        dim3 grid(DOUT / BN, NB / 2);
        snn_gemm_if<true><<<grid, 256, 0, stream>>>(A, W, Wn, bias, gamma, beta,
                                                    rmean, rvar, out);
    } else {
        dim3 grid(DOUT / BN, NB / 2);
        snn_gemm_if<false><<<grid, 256, 0, stream>>>(A, W, nullptr, bias, gamma, beta,
                                                     rmean, rvar, out);
    }
}

// Round 9
// 312.857 us; speedup vs baseline: 1.1939x; 1.1863x over previous
//
#include <hip/hip_runtime.h>
#include <hip/hip_bf16.h>

typedef float  float4v __attribute__((ext_vector_type(4)));
typedef short  short8v __attribute__((ext_vector_type(8)));
typedef short  short4v __attribute__((ext_vector_type(4)));
typedef __bf16 bf16x8  __attribute__((ext_vector_type(8)));
typedef float  f32x4   __attribute__((ext_vector_type(4)));
typedef float  f32x16  __attribute__((ext_vector_type(16)));

constexpr int NB = 512, T = 64, DIN = 1024, DOUT = 1024;
constexpr int BM = 128, BN = 128, BK = 64;

// ---- workspace layout (bf16 path) ----
constexpr size_t ABF_BYTES = (size_t)NB * T * DIN * 2;   // 67,108,864
constexpr size_t WN_BYTES  = (size_t)DOUT * DIN * 2;     // 2,097,152
constexpr size_t WS_BF16   = ABF_BYTES + WN_BYTES;       // ~69 MB

constexpr int A_BLOCKS = (NB * T * DIN) / 8 / 256;       // 16384
constexpr int W_BLOCKS = (DOUT * DIN) / 4 / 256;         // 1024

__device__ __forceinline__ short f2bf_rne(float x) {
    return __builtin_bit_cast(short, __float2bfloat16(x));
}
__device__ __forceinline__ short f2bf_trunc(float x) {   // exact for {0,1}
    return (short)(__builtin_bit_cast(unsigned int, x) >> 16);
}
__device__ __forceinline__ void load_lds_16B(const void* g, void* l) {
    __builtin_amdgcn_global_load_lds(
        (const __attribute__((address_space(1))) unsigned int*)g,
        (__attribute__((address_space(3))) unsigned int*)l, 16, 0, 0);
}

// ---- merged prepass: A fp32->bf16 (trunc, exact for {0,1}) + Wn fold ----
__global__ void __launch_bounds__(256)
prep_all_kernel(const float* __restrict__ A, const float* __restrict__ W,
                const float* __restrict__ gamma, const float* __restrict__ rvar,
                short* __restrict__ Abf, short* __restrict__ Wn) {
    int bid = blockIdx.x;
    if (bid < A_BLOCKS) {
        int idx = bid * 256 + threadIdx.x;               // 8-elem group
        const float4v* p = (const float4v*)A + (size_t)idx * 2;
        float4v v0 = __builtin_nontemporal_load(p);
        float4v v1 = __builtin_nontemporal_load(p + 1);
        short8v s;
        #pragma unroll
        for (int j = 0; j < 4; j++) {
            s[j]     = f2bf_trunc(v0[j]);
            s[j + 4] = f2bf_trunc(v1[j]);
        }
        *((short8v*)Abf + idx) = s;
    } else {
        int idx = (bid - A_BLOCKS) * 256 + threadIdx.x;  // float4 group
        int o = idx >> 8;
        float r = gamma[o] / sqrtf(rvar[o]);
        float4v w = ((const float4v*)W)[idx];
        short4v s;
        #pragma unroll
        for (int j = 0; j < 4; j++) s[j] = f2bf_rne(w[j] * r);
        ((short4v*)Wn)[idx] = s;
    }
}

// ---- main: 128x128 tile, 32x32x16 MFMA, full-DMA staging + IF scan
// grid (256, 8): all 8 column-blocks of a sample-pair land on one XCD
// (linear id % 8 == bs % 8) -> A tile is fetched from HBM ~once.
__global__ void __launch_bounds__(256, 4)
snn_gemm_if_v9(const short* __restrict__ Abf,  // (N*T, DIN) bf16 {0,1}
               const short* __restrict__ Wn,   // (DOUT, DIN) bf16, BN-folded
               const float* __restrict__ bias, const float* __restrict__ gamma,
               const float* __restrict__ beta, const float* __restrict__ rmean,
               const float* __restrict__ rvar, float* __restrict__ out) {
    __shared__ __align__(16) char smem[32768];   // A 16K + B 16K; potS union 32K
    __shared__ float bstepS[BN];
    char* AsS   = smem;                          // 1024 slots x 16B
    char* BsS   = smem + 16384;                  // 1024 slots x 16B
    float* potS = (float*)smem;                  // 64 x 128 fp32 (epilogue)

    const int tid = threadIdx.x;
    const int bs  = blockIdx.x;                  // sample pair; XCD = bs % 8
    const int oB  = blockIdx.y * BN;             // column block

    if (tid < BN) {
        int o = oB + tid;
        float r = gamma[o] / sqrtf(rvar[o]);
        bstepS[tid] = ((bias[o] - rmean[o]) * r + beta[o]) * (1.0f / 64.0f);
    }

    const int lane = tid & 63;
    const int wv   = tid >> 6;
    const int wr   = wv & 1;      // 64-row half == sample within pair
    const int wc   = wv >> 1;     // 64-col half
    const int l31  = lane & 31;
    const int half = lane >> 5;
    const int s7   = lane & 7;

    // staging: slot s -> row=s>>3, chunk=(s&7)^(row&7)  (16B chunks, 8/row)
    int srcOff[4];
    #pragma unroll
    for (int i = 0; i < 4; i++) {
        int s = i * 256 + tid, row = s >> 3, ck = (s & 7) ^ (row & 7);
        srcOff[i] = row * (DIN * 2) + ck * 16;
    }
    // fragment LDS offsets (32x32x16: m=lane&31, k=(lane>>5)*8+j)
    // row r, k-chunk c=ks*2+half -> slot r*8 + (c ^ (r&7)); (r&7)==s7 here.
    int aOff[2][4], bOff[2][4];
    #pragma unroll
    for (int i = 0; i < 2; i++) {
        int ra = wr * 64 + i * 32 + l31;
        int rb = wc * 64 + i * 32 + l31;
        #pragma unroll
        for (int ks = 0; ks < 4; ks++) {
            int c = ks * 2 + half;
            aOff[i][ks] = (ra * 8 + (c ^ s7)) * 16;
            bOff[i][ks] = (rb * 8 + (c ^ s7)) * 16;
        }
    }

    f32x16 acc[2][2] = {};
    const char* Ab = (const char*)(Abf + (size_t)bs * BM * DIN);
    const char* Bb = (const char*)(Wn + (size_t)oB * DIN);

    for (int kb = 0; kb < DIN; kb += BK) {
        __syncthreads();                         // prev tile ds_reads done
        #pragma unroll
        for (int i = 0; i < 4; i++) {
            int s = i * 256 + tid;
            load_lds_16B(Ab + srcOff[i] + kb * 2, AsS + s * 16);
            load_lds_16B(Bb + srcOff[i] + kb * 2, BsS + s * 16);
        }
        __syncthreads();                         // staged data visible

        #pragma unroll
        for (int ks = 0; ks < 4; ks++) {
            bf16x8 af[2], bf[2];
            #pragma unroll
            for (int i = 0; i < 2; i++)
                af[i] = __builtin_bit_cast(bf16x8, *(const short8v*)(AsS + aOff[i][ks]));
            #pragma unroll
            for (int i = 0; i < 2; i++)
                bf[i] = __builtin_bit_cast(bf16x8, *(const short8v*)(BsS + bOff[i][ks]));
            #pragma unroll
            for (int mi = 0; mi < 2; mi++)
                #pragma unroll
                for (int ni = 0; ni < 2; ni++)
                    acc[mi][ni] = __builtin_amdgcn_mfma_f32_32x32x16_bf16(
                        af[mi], bf[ni], acc[mi][ni], 0, 0, 0);
        }
    }

    __syncthreads();                             // staging free; potS aliases it

    // two 64-row chunks (sample s = wr half): acc -> potS, then IF scan.
    // C/D 32x32 layout: col=lane&31, row=(reg&3)+8*(reg>>2)+4*(lane>>5).
    // Writes: 32 consecutive cols/instr -> conflict-free; scan reads 2-way.
    #pragma unroll 1
    for (int s = 0; s < 2; s++) {
        if (wr == s) {
            #pragma unroll
            for (int mi = 0; mi < 2; mi++)
                #pragma unroll
                for (int ni = 0; ni < 2; ni++)
                    #pragma unroll
                    for (int reg = 0; reg < 16; reg++) {
                        int row = mi * 32 + (reg & 3) + 8 * (reg >> 2) + 4 * half;
                        int col = wc * 64 + ni * 32 + l31;
                        potS[row * BN + col] = acc[mi][ni][reg];
                    }
        }
        __syncthreads();
        if (tid < BN) {
            int n = bs * 2 + s;
            float pot = 0.f, cnt = 0.f;
            const float bst = bstepS[tid];
            float* so = out + (size_t)n * T * DOUT + oB + tid;
            for (int t = 0; t < T; t++) {
                pot += potS[t * BN + tid] + bst;
                float spk = (pot >= 1.0f) ? 1.0f : 0.0f;
                pot -= spk;
                cnt += spk;
                __builtin_nontemporal_store(spk, so + (size_t)t * DOUT);
            }
            __builtin_nontemporal_store(
                cnt, out + (size_t)NB * T * DOUT + (size_t)n * DOUT + oB + tid);
        }
        __syncthreads();
    }
}

// ===================== fallback (round-2 proven path) =====================

constexpr int LDA_F = 72;
constexpr int A_BYTES_F = BM * LDA_F * 2;
constexpr int SMEM_F = A_BYTES_F + BN * BK * 2;

__global__ void __launch_bounds__(256)
fold_w_kernel(const float* __restrict__ W, const float* __restrict__ gamma,
              const float* __restrict__ rvar, short* __restrict__ Wn) {
    int idx = blockIdx.x * 256 + threadIdx.x;
    int o = idx >> 8;
    float r = gamma[o] / sqrtf(rvar[o]);
    float4v w = ((const float4v*)W)[idx];
    short4v s;
    #pragma unroll
    for (int j = 0; j < 4; j++) s[j] = f2bf_rne(w[j] * r);
    ((short4v*)Wn)[idx] = s;
}

template <bool PREFOLD>
__global__ void __launch_bounds__(256)
snn_gemm_if(const float* __restrict__ A, const float* __restrict__ W,
            const short* __restrict__ Wn,
            const float* __restrict__ bias, const float* __restrict__ gamma,
            const float* __restrict__ beta, const float* __restrict__ rmean,
            const float* __restrict__ rvar, float* __restrict__ out) {
    __shared__ __align__(16) char smem[SMEM_F];
    __shared__ float ratioS[BN];
    __shared__ float bstepS[BN];
    short* AsS  = (short*)smem;
    short* BsS  = (short*)(smem + A_BYTES_F);
    float* potS = (float*)smem;

    const int tid   = threadIdx.x;
    const int by    = blockIdx.y;
    const int oBase = blockIdx.x * BN;

    if (tid < BN) {
        int o = oBase + tid;
        float r = gamma[o] / sqrtf(rvar[o]);
        ratioS[tid] = r;
        bstepS[tid] = ((bias[o] - rmean[o]) * r + beta[o]) * (1.0f / 64.0f);
    }
    __syncthreads();

    const int lane = tid & 63;
    const int wv   = tid >> 6;
    const int wr   = wv & 1;
    const int wc   = wv >> 1;
    const int l15  = lane & 15;
    const int quad = lane >> 4;

    f32x4 acc[4][4] = {};
    const float* Ab = A + (size_t)by * BM * DIN;

    for (int kb = 0; kb < DIN; kb += BK) {
        float4v av[4][2];
        #pragma unroll
        for (int i = 0; i < 4; i++) {
            int g = i * 256 + tid;
            int r = g >> 3, k8 = g & 7;
            const float4v* p = (const float4v*)(Ab + (size_t)r * DIN + kb + k8 * 8);
            av[i][0] = p[0];
            av[i][1] = p[1];
        }
        float4v bv[4][2];
        if constexpr (!PREFOLD) {
            #pragma unroll
            for (int i = 0; i < 4; i++) {
                int slot = i * 256 + tid;
                int r = slot >> 3, k8 = (slot & 7) ^ (r & 7);
                const float4v* p = (const float4v*)(W + (size_t)(oBase + r) * DIN + kb + k8 * 8);
                bv[i][0] = p[0];
                bv[i][1] = p[1];
            }
        }
        __syncthreads();

        if constexpr (PREFOLD) {
            #pragma unroll
            for (int i = 0; i < 4; i++) {
                int slot = i * 256 + tid;
                int r = slot >> 3, k8 = (slot & 7) ^ (r & 7);
                load_lds_16B(Wn + (size_t)(oBase + r) * DIN + kb + k8 * 8,
                             BsS + (size_t)slot * 8);
            }
        } else {
            #pragma unroll
            for (int i = 0; i < 4; i++) {
                int slot = i * 256 + tid;
                int r = slot >> 3;
                float rt = ratioS[r];
                short8v s;
                #pragma unroll
                for (int j = 0; j < 4; j++) {
                    s[j]     = f2bf_rne(bv[i][0][j] * rt);
                    s[j + 4] = f2bf_rne(bv[i][1][j] * rt);
                }
                *(short8v*)(BsS + (size_t)slot * 8) = s;
            }
        }
        #pragma unroll
        for (int i = 0; i < 4; i++) {
            int g = i * 256 + tid;
            int r = g >> 3, k8 = g & 7;
            short8v s;
            #pragma unroll
            for (int j = 0; j < 4; j++) {
                s[j]     = f2bf_trunc(av[i][0][j]);
                s[j + 4] = f2bf_trunc(av[i][1][j]);
            }
            *(short8v*)(&AsS[r * LDA_F + k8 * 8]) = s;
        }
        __syncthreads();

        #pragma unroll
        for (int ks = 0; ks < 2; ks++) {
            bf16x8 af[4], bfv[4];
            #pragma unroll
            for (int mi = 0; mi < 4; mi++)
                af[mi] = __builtin_bit_cast(bf16x8,
                    *(const short8v*)(&AsS[(wr * 64 + mi * 16 + l15) * LDA_F + ks * 32 + quad * 8]));
            #pragma unroll
            for (int ni = 0; ni < 4; ni++) {
                int row  = wc * 64 + ni * 16 + l15;
                int slot = row * 8 + ((ks * 4 + quad) ^ (l15 & 7));
                bfv[ni] = __builtin_bit_cast(bf16x8, *(const short8v*)(BsS + (size_t)slot * 8));
            }
            #pragma unroll
            for (int mi = 0; mi < 4; mi++)
                #pragma unroll
                for (int ni = 0; ni < 4; ni++)
                    acc[mi][ni] = __builtin_amdgcn_mfma_f32_16x16x32_bf16(
                        af[mi], bfv[ni], acc[mi][ni], 0, 0, 0);
        }
    }

    __syncthreads();

    #pragma unroll 1
    for (int s = 0; s < 2; s++) {
        if (wr == s) {
            #pragma unroll
            for (int mi = 0; mi < 4; mi++)
                #pragma unroll
                for (int ni = 0; ni < 4; ni++)
                    #pragma unroll
                    for (int r = 0; r < 4; r++)
                        potS[(mi * 16 + quad * 4 + r) * BN + wc * 64 + ni * 16 + l15] =
                            acc[mi][ni][r];
        }
        __syncthreads();
        if (tid < BN) {
            int n = by * 2 + s;
            float pot = 0.f, cnt = 0.f;
            const float bst = bstepS[tid];
            float* so = out + (size_t)n * T * DOUT + oBase + tid;
            for (int t = 0; t < T; t++) {
                pot += potS[t * BN + tid] + bst;
                float spk = (pot >= 1.0f) ? 1.0f : 0.0f;
                pot -= spk;
                cnt += spk;
                so[(size_t)t * DOUT] = spk;
            }
            out[(size_t)NB * T * DOUT + (size_t)n * DOUT + oBase + tid] = cnt;
        }
        __syncthreads();
    }
}

extern "C" void kernel_launch(void* const* d_in, const int* in_sizes, int n_in,
                              void* d_out, int out_size, void* d_ws, size_t ws_size,
                              hipStream_t stream) {
    const float* A     = (const float*)d_in[0];
    // d_in[1] (input_features_sc) feeds only the un-returned ANN path — dead.
    const float* W     = (const float*)d_in[2];
    const float* bias  = (const float*)d_in[3];
    const float* gamma = (const float*)d_in[4];
    const float* beta  = (const float*)d_in[5];
    const float* rmean = (const float*)d_in[6];
    const float* rvar  = (const float*)d_in[7];
    float* out = (float*)d_out;

    if (d_ws != nullptr && ws_size >= WS_BF16) {
        short* Abf = (short*)d_ws;
        short* Wn  = (short*)((char*)d_ws + ABF_BYTES);
        prep_all_kernel<<<A_BLOCKS + W_BLOCKS, 256, 0, stream>>>(A, W, gamma, rvar,
                                                                 Abf, Wn);
        dim3 grid(NB / 2, DOUT / BN);   // (256, 8): same-sample blocks -> same XCD
        snn_gemm_if_v9<<<grid, 256, 0, stream>>>(Abf, Wn, bias, gamma, beta,
                                                 rmean, rvar, out);
    } else if (d_ws != nullptr && ws_size >= WN_BYTES) {
        short* Wn = (short*)d_ws;
        fold_w_kernel<<<W_BLOCKS, 256, 0, stream>>>(W, gamma, rvar, Wn);
        dim3 grid(DOUT / BN, NB / 2);
        snn_gemm_if<true><<<grid, 256, 0, stream>>>(A, W, Wn, bias, gamma, beta,
                                                    rmean, rvar, out);
    } else {
        dim3 grid(DOUT / BN, NB / 2);
        snn_gemm_if<false><<<grid, 256, 0, stream>>>(A, W, nullptr, bias, gamma, beta,
                                                     rmean, rvar, out);
    }
}